// Round 4
// baseline (897.836 us; speedup 1.0000x reference)
//
#include <hip/hip_runtime.h>
#include <math.h>

#define N_NODES 15000
#define N_EDGES 40000
#define N_GRAPHS 750
#define N_TILES 938   // ceil(15000/16)

__device__ __forceinline__ float sigmoidf_(float x) { return 1.f / (1.f + expf(-x)); }

// ---------------- prep kernels ----------------
__global__ void count_kernel(const int* __restrict__ src, const int* __restrict__ dst,
                             int* __restrict__ tcnt, float* __restrict__ deg) {
    int e = blockIdx.x * 256 + threadIdx.x;
    if (e >= N_EDGES) return;
    atomicAdd(&tcnt[src[e] >> 4], 1);
    atomicAdd(&deg[dst[e]], 1.f);
}

// single-round scan over 938 tile counts
__global__ void tscan_kernel(const int* __restrict__ tcnt, int* __restrict__ tptr,
                             int* __restrict__ cursor) {
    __shared__ int buf[1024];
    int t = threadIdx.x;
    int v = (t < N_TILES) ? tcnt[t] : 0;
    buf[t] = v;
    __syncthreads();
    for (int ofs = 1; ofs < 1024; ofs <<= 1) {
        int a = (t >= ofs) ? buf[t - ofs] : 0;
        __syncthreads();
        buf[t] += a;
        __syncthreads();
    }
    if (t < N_TILES) {
        int excl = buf[t] - v;
        tptr[t] = excl;
        cursor[t] = excl;
    }
    if (t == N_TILES - 1) tptr[N_TILES] = buf[t];
}

__global__ void fill_kernel(const int* __restrict__ src, int* __restrict__ cursor,
                            int* __restrict__ edge_list) {
    int e = blockIdx.x * 256 + threadIdx.x;
    if (e >= N_EDGES) return;
    int slot = atomicAdd(&cursor[src[e] >> 4], 1);
    edge_list[slot] = e;
}

__global__ void gptr_kernel(const int* __restrict__ batch, int* __restrict__ gptr) {
    int n = blockIdx.x * 256 + threadIdx.x;
    if (n >= N_NODES) return;
    int b = batch[n];
    int pb = (n == 0) ? -1 : batch[n - 1];
    for (int g = pb + 1; g <= b; ++g) gptr[g] = n;
    if (n == N_NODES - 1)
        for (int g = b + 1; g <= N_GRAPHS; ++g) gptr[g] = N_NODES;
}

// 4 nodes per block, staged input, coalesced writes
__global__ __launch_bounds__(256)
void proj_kernel(const float* __restrict__ x, const float* __restrict__ W,
                 const float* __restrict__ b, float* __restrict__ node_h) {
    __shared__ float xs[4][32];
    int n0 = blockIdx.x * 4;
    int tid = threadIdx.x;
    if (tid < 128) xs[tid >> 5][tid & 31] = x[n0 * 32 + tid];
    __syncthreads();
    int nn = tid >> 6, f = tid & 63;
    float s = b[f];
    #pragma unroll
    for (int i = 0; i < 32; ++i) s += xs[nn][i] * W[i * 64 + f];
    node_h[(size_t)(n0 + nn) * 64 + f] = fmaxf(s, 0.f);
}

// 4 edges per block, staged edge_attr, coalesced writes
__global__ __launch_bounds__(256)
void h1_kernel(const float* __restrict__ ea, const float* __restrict__ W,
               const float* __restrict__ b, float* __restrict__ h1) {
    __shared__ float eas[4][16];
    int e0 = blockIdx.x * 4;
    int tid = threadIdx.x;
    if (tid < 64) eas[tid >> 4][tid & 15] = ea[e0 * 16 + tid];
    __syncthreads();
    int nn = tid >> 6, f = tid & 63;
    float s = b[f];
    #pragma unroll
    for (int i = 0; i < 16; ++i) s += eas[nn][i] * W[i * 64 + f];
    h1[(size_t)(e0 + nn) * 64 + f] = fmaxf(s, 0.f);
}

// Pack e2_W into coalesced per-lane stream layout for f-tile-16 conv:
// flat float4 idx = (ft*64 + d)*256 + pp*2 + u ; value = e2W[k=pp>>1][d*64 + ft*16 + (pp&1)*8 + u*4]
__global__ void pack_kernel(const float* __restrict__ e2W, float4* __restrict__ Bp4) {
    int idx = blockIdx.x * 256 + threadIdx.x;  // 65536 float4s
    if (idx >= 4 * 64 * 256) return;
    int u = idx & 1, pp = (idx >> 1) & 127, d = (idx >> 8) & 63, ft = idx >> 14;
    int k = pp >> 1, fo = (pp & 1) * 8 + u * 4;
    Bp4[idx] = *(const float4*)(e2W + (size_t)k * 4096 + d * 64 + ft * 16 + fo);
}

// Transpose recurrent weights for coalesced per-lane row access
__global__ void tpose_kernel(const float* __restrict__ lWih, const float* __restrict__ lWhh,
                             const float* __restrict__ gWih, const float* __restrict__ gWhh,
                             float* __restrict__ lWihT, float* __restrict__ lWhhT,
                             float* __restrict__ gWihT, float* __restrict__ gWhhT) {
    int idx = blockIdx.x * 256 + threadIdx.x;
    if (idx < 32768) {                       // lWih [256][128] -> [128][256]
        int i = idx >> 8, r = idx & 255;
        lWihT[i * 256 + r] = lWih[r * 128 + i];
    } else if (idx < 49152) {                // lWhh [256][64] -> [64][256]
        int x2 = idx - 32768; int i = x2 >> 8, r = x2 & 255;
        lWhhT[i * 256 + r] = lWhh[r * 64 + i];
    } else if (idx < 61440) {                // gWih [192][64] -> [64][192]
        int x2 = idx - 49152; int i = x2 / 192, r = x2 % 192;
        gWihT[i * 192 + r] = gWih[r * 64 + i];
    } else if (idx < 73728) {                // gWhh [192][64] -> [64][192]
        int x2 = idx - 61440; int i = x2 / 192, r = x2 % 192;
        gWhhT[i * 192 + r] = gWhh[r * 64 + i];
    }
}

// Tb[n,f] = sum_d node_h[n,d] * e2b[d*64+f]
__global__ __launch_bounds__(256)
void tb_kernel(const float* __restrict__ node_h, const float* __restrict__ e2b,
               float* __restrict__ Tb_g) {
    __shared__ float hrow[4][64];
    int nb = blockIdx.x * 4;
    int tid = threadIdx.x;
    int nn = tid >> 6, f = tid & 63;
    hrow[nn][f] = node_h[(size_t)(nb + nn) * 64 + f];
    __syncthreads();
    float s = 0.f;
    #pragma unroll 8
    for (int d = 0; d < 64; ++d) s += hrow[nn][d] * e2b[d * 64 + f];
    Tb_g[(size_t)(nb + nn) * 64 + f] = s;
}

// ---------------- fused conv: 16 nodes x 16 f per block ----------------
// Phase A: thread owns (k, 8 f's): per d4-iter 8 broadcast ds_read_b128 feed 256 FMAs
//          (LDS/FMA = 0.75 -> FMA-bound). B reg-double-buffered from packed stream.
// Phase B: flat tile edge range, 16 slots x 16 fi; dot64 via ds_read_b128.
__global__ __launch_bounds__(256, 2)
void conv_kernel(const float* __restrict__ node_h, const float* __restrict__ h1,
                 const float4* __restrict__ Bp4, const float* __restrict__ Tb_g,
                 const int* __restrict__ tptr, const int* __restrict__ edge_list,
                 const int* __restrict__ src, const int* __restrict__ dst,
                 float* __restrict__ agg) {
    __shared__ float A_s[16][64];
    __shared__ float Tb_s[16][16];
    __shared__ float T_lds[16 * 1060];   // [node]*1060 + [fi]*66 + k  (bank-spread pads)
    int bid = blockIdx.x;
    int nt = bid >> 2, ft = bid & 3;
    int n0 = nt * 16, f0 = ft * 16;
    int tid = threadIdx.x;

    {   // stage A-tile: one float4 per thread, coalesced
        int nn = tid >> 4, d4 = (tid & 15) * 4;
        int n = n0 + nn;
        float4 v = make_float4(0.f, 0.f, 0.f, 0.f);
        if (n < N_NODES) v = *(const float4*)(node_h + (size_t)n * 64 + d4);
        *(float4*)(&A_s[nn][d4]) = v;
    }
    {   // stage Tb: 16 nodes x 16 f
        int nn = tid >> 4, fi = tid & 15;
        int n = n0 + nn;
        Tb_s[nn][fi] = (n < N_NODES) ? Tb_g[(size_t)n * 64 + f0 + fi] : 0.f;
    }
    __syncthreads();

    int pn = tid >> 7;                   // node half (0/1)
    int pp = tid & 127;
    int k = pp >> 1;
    int fo = (pp & 1) * 8;               // this thread's 8 f's within the 16-wide tile
    int nb = pn * 8;
    const float4* BpP = Bp4 + (size_t)(ft * 64) * 256 + pp * 2;

    float acc[8][8];
    #pragma unroll
    for (int a = 0; a < 8; ++a)
        #pragma unroll
        for (int b = 0; b < 8; ++b) acc[a][b] = 0.f;

    float4 bpre[8];
    #pragma unroll
    for (int dd = 0; dd < 4; ++dd) {
        bpre[dd * 2]     = BpP[(size_t)dd * 256];
        bpre[dd * 2 + 1] = BpP[(size_t)dd * 256 + 1];
    }

    for (int d4 = 0; d4 < 64; d4 += 4) {
        float4 bcur[8];
        #pragma unroll
        for (int q = 0; q < 8; ++q) bcur[q] = bpre[q];
        if (d4 < 60) {
            #pragma unroll
            for (int dd = 0; dd < 4; ++dd) {
                bpre[dd * 2]     = BpP[(size_t)(d4 + 4 + dd) * 256];
                bpre[dd * 2 + 1] = BpP[(size_t)(d4 + 4 + dd) * 256 + 1];
            }
        }
        float4 A8[8];
        #pragma unroll
        for (int nn = 0; nn < 8; ++nn) A8[nn] = *(const float4*)(&A_s[nb + nn][d4]);
        #pragma unroll
        for (int dd = 0; dd < 4; ++dd) {
            float bv[8] = {bcur[dd*2].x, bcur[dd*2].y, bcur[dd*2].z, bcur[dd*2].w,
                           bcur[dd*2+1].x, bcur[dd*2+1].y, bcur[dd*2+1].z, bcur[dd*2+1].w};
            #pragma unroll
            for (int nn = 0; nn < 8; ++nn) {
                float a = (&A8[nn].x)[dd];
                #pragma unroll
                for (int j = 0; j < 8; ++j) acc[nn][j] += a * bv[j];
            }
        }
    }
    #pragma unroll
    for (int nn = 0; nn < 8; ++nn)
        #pragma unroll
        for (int j = 0; j < 8; ++j)
            T_lds[(nb + nn) * 1060 + (fo + j) * 66 + k] = acc[nn][j];
    __syncthreads();

    // Phase B: flat edge range for the whole 16-node tile
    int fi = tid & 15, slot = tid >> 4;   // 16 edge slots x 16 f
    int te0 = tptr[nt], te1 = tptr[nt + 1];
    for (int c = te0 + slot; c < te1; c += 16) {
        int e = edge_list[c];
        int nn = src[e] - n0;
        const float* h1e = h1 + (size_t)e * 64;
        const float* Tr = &T_lds[nn * 1060 + fi * 66];
        float s = Tb_s[nn][fi];
        #pragma unroll
        for (int k4 = 0; k4 < 64; k4 += 4) {
            float4 h4 = *(const float4*)(h1e + k4);
            float4 tv = *(const float4*)(Tr + k4);
            s += h4.x * tv.x + h4.y * tv.y + h4.z * tv.z + h4.w * tv.w;
        }
        atomicAdd(&agg[(size_t)dst[e] * 64 + f0 + fi], s);
    }
}

// ---------------- GRU: transposed weights (coalesced), b128 LDS reads ----------------
__global__ __launch_bounds__(192)
void gru_kernel(float* __restrict__ node_h, const float* __restrict__ agg,
                const float* __restrict__ deg, const float* __restrict__ conv_b,
                const float* __restrict__ WihT, const float* __restrict__ WhhT,
                const float* __restrict__ bih, const float* __restrict__ bhh) {
    __shared__ float m_s[64], h_s[64], gi_s[192], gh_s[192];
    int j = threadIdx.x;  // 0..191 (gate-row)
    float wih[64], whh[64];
    #pragma unroll
    for (int d = 0; d < 64; ++d) {
        wih[d] = WihT[d * 192 + j];   // coalesced: lanes j consecutive
        whh[d] = WhhT[d * 192 + j];
    }
    float bi = bih[j], bh = bhh[j];
    for (int n = blockIdx.x; n < N_NODES; n += gridDim.x) {
        if (j < 64) {
            float dg = fmaxf(deg[n], 1.f);
            m_s[j] = fmaxf(agg[(size_t)n * 64 + j] / dg + conv_b[j], 0.f);
            h_s[j] = node_h[(size_t)n * 64 + j];
        }
        __syncthreads();
        float gi = bi, gh = bh;
        #pragma unroll
        for (int d4 = 0; d4 < 64; d4 += 4) {
            float4 m4 = *(const float4*)(&m_s[d4]);
            float4 h4 = *(const float4*)(&h_s[d4]);
            gi += m4.x * wih[d4] + m4.y * wih[d4 + 1] + m4.z * wih[d4 + 2] + m4.w * wih[d4 + 3];
            gh += h4.x * whh[d4] + h4.y * whh[d4 + 1] + h4.z * whh[d4 + 2] + h4.w * whh[d4 + 3];
        }
        gi_s[j] = gi; gh_s[j] = gh;
        __syncthreads();
        if (j < 64) {
            float r = sigmoidf_(gi_s[j] + gh_s[j]);
            float z = sigmoidf_(gi_s[j + 64] + gh_s[j + 64]);
            float nn = tanhf(gi_s[j + 128] + r * gh_s[j + 128]);
            node_h[(size_t)n * 64 + j] = (1.f - z) * nn + z * h_s[j];
        }
        __syncthreads();
    }
}

// ---------------- Set2Set step: transposed LSTM weights, online-softmax attention ----------------
__global__ __launch_bounds__(64)
void s2s_kernel(const float* __restrict__ node_h, const int* __restrict__ gptr,
                float* __restrict__ hl, float* __restrict__ cl, float* __restrict__ q_star,
                const float* __restrict__ WihT, const float* __restrict__ WhhT,
                const float* __restrict__ bih, const float* __restrict__ bhh) {
    int g = blockIdx.x, t = threadIdx.x;
    __shared__ float qs[128], hs[64], q[64], wts[64];
    qs[t] = q_star[g * 128 + t];
    qs[64 + t] = q_star[g * 128 + 64 + t];
    hs[t] = hl[g * 64 + t];
    __syncthreads();
    float gv[4];
    #pragma unroll
    for (int gate = 0; gate < 4; ++gate) {
        int row = gate * 64 + t;
        float s = bih[row] + bhh[row];
        #pragma unroll 8
        for (int i = 0; i < 128; ++i) s += qs[i] * WihT[i * 256 + row];   // coalesced
        #pragma unroll 8
        for (int i = 0; i < 64; ++i) s += hs[i] * WhhT[i * 256 + row];    // coalesced
        gv[gate] = s;
    }
    float c = sigmoidf_(gv[1]) * cl[g * 64 + t] + sigmoidf_(gv[0]) * tanhf(gv[2]);
    float hn = sigmoidf_(gv[3]) * tanhf(c);
    cl[g * 64 + t] = c;
    hl[g * 64 + t] = hn;
    q[t] = hn;
    __syncthreads();
    int nbeg = gptr[g], nend = gptr[g + 1];
    float rm = -INFINITY, rs = 0.f, racc = 0.f;
    for (int base = nbeg; base < nend; base += 64) {
        int n = base + t;
        float e = -INFINITY;
        if (n < nend) {
            float s = 0.f;
            #pragma unroll 8
            for (int f = 0; f < 64; ++f) s += node_h[(size_t)n * 64 + f] * q[f];
            e = s;
        }
        float cm = e;
        #pragma unroll
        for (int o = 32; o > 0; o >>= 1) cm = fmaxf(cm, __shfl_down(cm, o));
        cm = __shfl(cm, 0);
        float nm = fmaxf(rm, cm);
        float scale = (rm == -INFINITY) ? 0.f : expf(rm - nm);
        float wv = (n < nend) ? expf(e - nm) : 0.f;
        float cs = wv;
        #pragma unroll
        for (int o = 32; o > 0; o >>= 1) cs += __shfl_down(cs, o);
        cs = __shfl(cs, 0);
        wts[t] = wv;
        __syncthreads();
        float na = racc * scale;
        int cnt2 = min(64, nend - base);
        for (int l = 0; l < cnt2; ++l) na += wts[l] * node_h[(size_t)(base + l) * 64 + t];
        racc = na;
        rs = rs * scale + cs;
        rm = nm;
        __syncthreads();
    }
    float r = (nend > nbeg) ? racc / rs : 0.f;
    q_star[g * 128 + t] = q[t];
    q_star[g * 128 + 64 + t] = r;
}

// ---------------- output MLP ----------------
__global__ __launch_bounds__(128)
void out_kernel(const float* __restrict__ q_star, const float* __restrict__ W1,
                const float* __restrict__ b1, const float* __restrict__ W2,
                const float* __restrict__ b2, float* __restrict__ z) {
    int g = blockIdx.x, j = threadIdx.x;
    __shared__ float qs[128], red[128];
    qs[j] = q_star[g * 128 + j];
    __syncthreads();
    float s = b1[j];
    #pragma unroll 8
    for (int i = 0; i < 128; ++i) s += qs[i] * W1[i * 128 + j];
    red[j] = fmaxf(s, 0.f) * W2[j];
    __syncthreads();
    for (int o = 64; o > 0; o >>= 1) {
        if (j < o) red[j] += red[j + o];
        __syncthreads();
    }
    if (j == 0) z[g] = red[0] + b2[0];
}

extern "C" void kernel_launch(void* const* d_in, const int* in_sizes, int n_in,
                              void* d_out, int out_size, void* d_ws, size_t ws_size,
                              hipStream_t stream) {
    const float* x         = (const float*)d_in[0];
    const float* edge_attr = (const float*)d_in[1];
    const int*   ei        = (const int*)d_in[2];
    const int*   batch     = (const int*)d_in[3];
    const float* in_W      = (const float*)d_in[4];
    const float* in_b      = (const float*)d_in[5];
    const float* e1_W      = (const float*)d_in[6];
    const float* e1_b      = (const float*)d_in[7];
    const float* e2_W      = (const float*)d_in[8];
    const float* e2_b      = (const float*)d_in[9];
    const float* conv_b    = (const float*)d_in[10];
    const float* gWih      = (const float*)d_in[11];
    const float* gWhh      = (const float*)d_in[12];
    const float* gbih      = (const float*)d_in[13];
    const float* gbhh      = (const float*)d_in[14];
    const float* lWih      = (const float*)d_in[15];
    const float* lWhh      = (const float*)d_in[16];
    const float* lbih      = (const float*)d_in[17];
    const float* lbhh      = (const float*)d_in[18];
    const float* o1W       = (const float*)d_in[19];
    const float* o1b       = (const float*)d_in[20];
    const float* o2W       = (const float*)d_in[21];
    const float* o2b       = (const float*)d_in[22];
    const int* src = ei;
    const int* dst = ei + N_EDGES;
    float* z = (float*)d_out;

    char* ws = (char*)d_ws;
    size_t off = 0;
    auto alloc = [&](size_t bytes) {
        void* p = ws + off;
        off = (off + bytes + 255) & ~(size_t)255;
        return p;
    };
    float* node_h   = (float*)alloc((size_t)N_NODES * 64 * 4);
    float* agg      = (float*)alloc((size_t)N_NODES * 64 * 4);
    float* h1       = (float*)alloc((size_t)N_EDGES * 64 * 4);
    float* Bp       = (float*)alloc((size_t)4 * 64 * 256 * 4 * 4);   // packed e2_W, 1 MB
    float* Tb_g     = (float*)alloc((size_t)N_NODES * 64 * 4);
    float* lWihT    = (float*)alloc(128 * 256 * 4);
    float* lWhhT    = (float*)alloc(64 * 256 * 4);
    float* gWihT    = (float*)alloc(64 * 192 * 4);
    float* gWhhT    = (float*)alloc(64 * 192 * 4);
    float* deg      = (float*)alloc(N_NODES * 4);       // deg,tcnt adjacent (one memset)
    int*   tcnt     = (int*)alloc((N_TILES + 2) * 4);
    int*   tcursor  = (int*)alloc((N_TILES + 2) * 4);
    int*   tptr     = (int*)alloc((N_TILES + 1) * 4);
    int*   edge_list= (int*)alloc(N_EDGES * 4);
    int*   gptr     = (int*)alloc((N_GRAPHS + 1) * 4);
    float* hl       = (float*)alloc(N_GRAPHS * 64 * 4); // hl,cl,q_star adjacent (one memset)
    float* cl       = (float*)alloc(N_GRAPHS * 64 * 4);
    float* q_star   = (float*)alloc(N_GRAPHS * 128 * 4);

    size_t degpad = ((size_t)N_NODES * 4 + 255) & ~(size_t)255;
    hipMemsetAsync(deg, 0, degpad + (N_TILES + 2) * 4, stream);             // deg + tcnt
    hipMemsetAsync(hl, 0, (size_t)N_GRAPHS * (64 + 64 + 128) * 4, stream);  // hl + cl + q_star

    count_kernel<<<(N_EDGES + 255) / 256, 256, 0, stream>>>(src, dst, tcnt, deg);
    tscan_kernel<<<1, 1024, 0, stream>>>(tcnt, tptr, tcursor);
    fill_kernel<<<(N_EDGES + 255) / 256, 256, 0, stream>>>(src, tcursor, edge_list);
    gptr_kernel<<<(N_NODES + 255) / 256, 256, 0, stream>>>(batch, gptr);
    proj_kernel<<<N_NODES / 4, 256, 0, stream>>>(x, in_W, in_b, node_h);
    h1_kernel<<<N_EDGES / 4, 256, 0, stream>>>(edge_attr, e1_W, e1_b, h1);
    pack_kernel<<<256, 256, 0, stream>>>(e2_W, (float4*)Bp);
    tpose_kernel<<<288, 256, 0, stream>>>(lWih, lWhh, gWih, gWhh, lWihT, lWhhT, gWihT, gWhhT);
    tb_kernel<<<N_NODES / 4, 256, 0, stream>>>(node_h, e2_b, Tb_g);

    for (int it = 0; it < 3; ++it) {
        hipMemsetAsync(agg, 0, (size_t)N_NODES * 64 * 4, stream);
        conv_kernel<<<N_TILES * 4, 256, 0, stream>>>(node_h, h1, (const float4*)Bp, Tb_g,
                                                     tptr, edge_list, src, dst, agg);
        gru_kernel<<<512, 192, 0, stream>>>(node_h, agg, deg, conv_b, gWihT, gWhhT, gbih, gbhh);
        if (it < 2)
            tb_kernel<<<N_NODES / 4, 256, 0, stream>>>(node_h, e2_b, Tb_g);
    }
    for (int st = 0; st < 3; ++st)
        s2s_kernel<<<N_GRAPHS, 64, 0, stream>>>(node_h, gptr, hl, cl, q_star,
                                                lWihT, lWhhT, lbih, lbhh);
    out_kernel<<<N_GRAPHS, 128, 0, stream>>>(q_star, o1W, o1b, o2W, o2b, z);
}